// Round 22
// baseline (548.997 us; speedup 1.0000x reference)
//
#include <hip/hip_runtime.h>

typedef __attribute__((ext_vector_type(4))) float f32x4;
typedef __attribute__((ext_vector_type(8))) __bf16 bf16x8;
typedef __attribute__((ext_vector_type(8))) unsigned short u16x8;

#define DI __device__ __forceinline__

constexpr int S_LEN = 4096;
constexpr int NBATCH = 4;
constexpr int HD = 1024;
constexpr int MROWS = NBATCH * S_LEN;  // 16384
constexpr int NCHUNK = 128;
constexpr int CHUNKL = 32;

DI float bf2f(unsigned short u) {
  unsigned int x = ((unsigned int)u) << 16;
  return __builtin_bit_cast(float, x);
}
DI unsigned short f2bf(float f) {
  unsigned int u = __builtin_bit_cast(unsigned int, f);
  u += 0x7FFFu + ((u >> 16) & 1u);  // RNE; inputs finite
  return (unsigned short)(u >> 16);
}
DI float sigmoid_f(float x) { return 1.0f / (1.0f + expf(-x)); }
DI float gelu_f(float x) {
  float u = 0.7978845608028654f * (x + 0.044715f * x * x * x);
  return 0.5f * x * (1.0f + tanhf(u));
}
DI void gload16(const void* g, void* l) {
  __builtin_amdgcn_global_load_lds(
      (const __attribute__((address_space(1))) unsigned int*)g,
      (__attribute__((address_space(3))) unsigned int*)l, 16, 0, 0);
}

// ---------------- weight transpose+convert: dst[n][k] = bf16(src[k][n]) ----
struct TDesc {
  const float* src;       // [1024][1024] row-major
  unsigned short* dst;    // bf16 bits
  int ldDst;
  int rowOff;
  int colOff;
};
struct TArgs { TDesc d[9]; };

__global__ __launch_bounds__(256) void transpose_pack(TArgs args) {
  const int w = blockIdx.x >> 8;
  const int tile = blockIdx.x & 255;
  TDesc dd = args.d[w];
  const int tn = (tile & 15) * 64;
  const int tk = (tile >> 4) * 64;
  __shared__ float t[64][65];
  const int tx = threadIdx.x & 63, ty = threadIdx.x >> 6;
#pragma unroll
  for (int r = 0; r < 16; ++r) {
    int kk = ty * 16 + r;
    t[kk][tx] = dd.src[(size_t)(tk + kk) * 1024 + tn + tx];
  }
  __syncthreads();
#pragma unroll
  for (int r = 0; r < 16; ++r) {
    int nn = ty * 16 + r;
    dd.dst[(size_t)(dd.rowOff + tn + nn) * dd.ldDst + dd.colOff + tk + tx] =
        f2bf(t[tx][nn]);
  }
}

// ---------------- bias packing (+ sigmoid(a_logit) tables) ----------------
__global__ __launch_bounds__(256) void bias_pack(
    const float* bxf, const float* bxb, const float* bgxf, const float* bgaf,
    const float* bgxb, const float* bgab, const float* bof, const float* bob,
    const float* falog, const float* balog, float* b1, float* bgf, float* bgb,
    float* bos, float* aef, float* aeb) {
  int i = blockIdx.x * 256 + threadIdx.x;
  if (i < 1024) {
    b1[i] = bxf[i];
    bgf[i] = bgxf[i];
    bgb[i] = bgxb[i];
    bos[i] = bof[i] + bob[i];
    aef[i] = sigmoid_f(falog[i]);
    aeb[i] = sigmoid_f(balog[i]);
  } else if (i < 2048) {
    int j = i - 1024;
    b1[i] = bxb[j];
    bgf[i] = bgaf[j];
    bgb[i] = bgab[j];
  }
}

// ---------------- gelu(x) -> bf16 (+ bf16 copy of x) ----------------------
__global__ __launch_bounds__(256) void gelu_in(const float4* __restrict__ x,
                                               ushort4* __restrict__ xg,
                                               ushort4* __restrict__ xr) {
  int i = blockIdx.x * 256 + threadIdx.x;
  float4 v = x[i];
  ushort4 o;
  o.x = f2bf(gelu_f(v.x));
  o.y = f2bf(gelu_f(v.y));
  o.z = f2bf(gelu_f(v.z));
  o.w = f2bf(gelu_f(v.w));
  xg[i] = o;
  if (xr) {
    ushort4 p;
    p.x = f2bf(v.x);
    p.y = f2bf(v.y);
    p.z = f2bf(v.z);
    p.w = f2bf(v.w);
    xr[i] = p;
  }
}

// ---------------- GEMM: C = A[M x K] * BT[N x K]^T, fused epilogues --------
// R21 engine (vectorized epilogue: thread owns 4 consecutive cols via
// bv[j] <- B row wn+4r+j). This round: B LDS swizzle reverted to the
// f(R)=R&7 family (measured 0-conflict for 8 rounds) on BOTH sides
// (rule #21); read slot = (ks4+g)^((4r+j)&7), staging sg = (t&7)^((t>>3)&7).
enum { EPI_BF16 = 0, EPI_X2 = 2, EPI_FINAL = 3, EPI_GATE = 4 };

template <int EPI, bool AUXBF = false>
__global__ __launch_bounds__(512, 4) void gemm_bt(
    const unsigned short* __restrict__ A, int lda,
    const unsigned short* __restrict__ BT, int K, int nbx,
    const float* __restrict__ bias, const void* __restrict__ aux,
    const float* __restrict__ bias2, float* __restrict__ fout,
    unsigned short* __restrict__ bout, int ldo) {
  constexpr int BK = 64;
  __shared__ __align__(16) unsigned short lA[256 * BK];  // 32 KB
  __shared__ __align__(16) unsigned short lB[128 * BK];  // 16 KB
  const int t = threadIdx.x;
  const int lane = t & 63, wave = t >> 6;
  const int nwg = gridDim.x;  // multiple of 8
  int wg = blockIdx.x;
  wg = (wg & 7) * (nwg >> 3) + (wg >> 3);  // XCD-chunked, bijective
  const int by = wg / nbx, bx = wg - by * nbx;
  const int m0 = by * 256, n0 = bx * 128;
  const int wm = (wave >> 1) * 64, wn = (wave & 1) * 64;  // 4M x 2N
  f32x4 acc[4][4] = {};
  const int Rs = t >> 3;  // 0..63
  const int sg = (t & 7) ^ (Rs & 7);  // f(R)=R&7, j-invariant (rows +64k)
  const unsigned short* Ag = A + (size_t)(m0 + Rs) * lda + sg * 8;
  const unsigned short* Bg = BT + (size_t)(n0 + Rs) * K + sg * 8;
  const int r = lane & 15, g = lane >> 4;
  const int nK = K / BK;

  for (int kt = 0; kt < nK; ++kt) {
    __syncthreads();  // WAR
    {
      const unsigned short* a0 = Ag + kt * BK;
      const unsigned short* b0 = Bg + kt * BK;
      unsigned short* lAp = lA + t * 8;
      unsigned short* lBp = lB + t * 8;
#pragma unroll
      for (int j = 0; j < 4; ++j)
        gload16(a0 + (size_t)(j * 64) * lda, lAp + j * 4096);
#pragma unroll
      for (int j = 0; j < 2; ++j)
        gload16(b0 + (size_t)(j * 64) * K, lBp + j * 4096);
    }
    __syncthreads();  // RAW (vmcnt0 drain)
#pragma unroll
    for (int ks = 0; ks < 2; ++ks) {
      bf16x8 af[4], bv[4];
#pragma unroll
      for (int i = 0; i < 4; ++i) {
        const int R = wm + i * 16 + r;
        af[i] = __builtin_bit_cast(
            bf16x8,
            *(const u16x8*)&lA[R * BK + ((ks * 4 + g) ^ (R & 7)) * 8]);
      }
#pragma unroll
      for (int j = 0; j < 4; ++j) {
        const int R = wn + 4 * r + j;  // 4 consecutive cols per thread
        bv[j] = __builtin_bit_cast(
            bf16x8,
            *(const u16x8*)&lB[R * BK + ((ks * 4 + g) ^ (R & 7)) * 8]);
      }
#pragma unroll
      for (int i = 0; i < 4; ++i)
#pragma unroll
        for (int j = 0; j < 4; ++j)
          acc[i][j] = __builtin_amdgcn_mfma_f32_16x16x32_bf16(
              af[i], bv[j], acc[i][j], 0, 0, 0);
    }
  }

  // epilogue: thread owns cols cb..cb+3 (consecutive) x rows (i,q)
  const int g4 = g * 4;
  const int cb = n0 + wn + 4 * r;
  const float4 bc4 = *(const float4*)&bias[cb];
  const float bcv[4] = {bc4.x, bc4.y, bc4.z, bc4.w};
#pragma unroll
  for (int i = 0; i < 4; ++i) {
#pragma unroll
    for (int q = 0; q < 4; ++q) {
      const int row = m0 + wm + i * 16 + g4 + q;
      const size_t o = (size_t)row * ldo + cb;
      float v[4];
#pragma unroll
      for (int j = 0; j < 4; ++j) v[j] = acc[i][j][q] + bcv[j];
      if constexpr (EPI == EPI_BF16) {
        ushort4 st = {f2bf(v[0]), f2bf(v[1]), f2bf(v[2]), f2bf(v[3])};
        *(ushort4*)&bout[o] = st;
      } else if constexpr (EPI == EPI_GATE) {
        if (cb < 1024) {
          // U = sig(gx_pre) * x1 ; aux = x1 (bf16, same layout as C)
          const ushort4 xa = *(const ushort4*)&((const unsigned short*)aux)[o];
          ushort4 st = {f2bf(sigmoid_f(v[0]) * bf2f(xa.x)),
                        f2bf(sigmoid_f(v[1]) * bf2f(xa.y)),
                        f2bf(sigmoid_f(v[2]) * bf2f(xa.z)),
                        f2bf(sigmoid_f(v[3]) * bf2f(xa.w))};
          *(ushort4*)&bout[o] = st;
        } else {
          // Am1 = 1 - a ; a = sig(ga_pre) * sig(a_logit)
          const float4 a4 = *(const float4*)&bias2[cb - 1024];
          const float ae[4] = {a4.x, a4.y, a4.z, a4.w};
          ushort4 st;
          unsigned short* sp = (unsigned short*)&st;
#pragma unroll
          for (int j = 0; j < 4; ++j)
            sp[j] = f2bf(1.0f - sigmoid_f(v[j]) * ae[j]);
          *(ushort4*)&bout[o] = st;
        }
      } else {
        float av[4];
        if constexpr (AUXBF) {
          const ushort4 xa = *(const ushort4*)&((const unsigned short*)aux)[o];
          av[0] = bf2f(xa.x); av[1] = bf2f(xa.y);
          av[2] = bf2f(xa.z); av[3] = bf2f(xa.w);
        } else {
          const float4 xa = *(const float4*)&((const float*)aux)[o];
          av[0] = xa.x; av[1] = xa.y; av[2] = xa.z; av[3] = xa.w;
        }
        if constexpr (EPI == EPI_X2) {
          ushort4 st;
          unsigned short* sp = (unsigned short*)&st;
#pragma unroll
          for (int j = 0; j < 4; ++j)
            sp[j] = f2bf(gelu_f(0.5f * v[j] + av[j]));
          *(ushort4*)&bout[o] = st;
        } else {  // EPI_FINAL
          float4 st = {v[0] + av[0], v[1] + av[1], v[2] + av[2], v[3] + av[3]};
          *(float4*)&fout[o] = st;
        }
      }
    }
  }
}

// ---------------- chunked linear scan h_t = a*h + xin ----------------------
// gates buffer: cols 0-1023 = U (sig(gx)*x1), cols 1024-2047 = Am1 = 1-a.
// a = 1-Am1; xin = sqrt(Am1*(2-Am1)) * U  (== sqrt(1-a^2)*gx*x1).
template <int REV>
__global__ __launch_bounds__(256) void scan_p1(
    const unsigned short* __restrict__ gates, float* __restrict__ Pf,
    float* __restrict__ Ee) {
  const int c0 = threadIdx.x * 4;
  const int chunk = blockIdx.y, b = blockIdx.z;
  float h[4] = {0.f, 0.f, 0.f, 0.f}, P[4] = {1.f, 1.f, 1.f, 1.f};
  for (int i = 0; i < CHUNKL; ++i) {
    const int p = chunk * CHUNKL + i;
    const int s = REV ? (S_LEN - 1 - p) : p;
    const size_t row = (size_t)b * S_LEN + s;
    const ushort4 Uv = *(const ushort4*)&gates[row * 2048 + c0];
    const ushort4 Av = *(const ushort4*)&gates[row * 2048 + 1024 + c0];
    const unsigned short* Up = (const unsigned short*)&Uv;
    const unsigned short* Ap = (const unsigned short*)&Av;
#pragma unroll
    for (int k = 0; k < 4; ++k) {
      const float am1 = bf2f(Ap[k]);
      const float a = 1.0f - am1;
      const float xin =
          sqrtf(fmaxf(0.f, am1 * (2.0f - am1))) * bf2f(Up[k]);
      h[k] = fmaf(a, h[k], xin);
      P[k] *= a;
    }
  }
  const size_t idx = ((size_t)b * NCHUNK + chunk) * HD + c0;
#pragma unroll
  for (int k = 0; k < 4; ++k) {
    Pf[idx + k] = P[k];
    Ee[idx + k] = h[k];
  }
}

// 1 channel/thread, 64-thread blocks, grid (16, NBATCH) = 64 blocks.
__global__ __launch_bounds__(64) void scan_p2(const float* __restrict__ Pf,
                                              const float* __restrict__ Ee,
                                              float* __restrict__ Ci) {
  const int c = blockIdx.x * 64 + threadIdx.x;
  const int b = blockIdx.y;
  float carry = 0.f;
#pragma unroll 4
  for (int j = 0; j < NCHUNK; ++j) {
    const size_t idx = ((size_t)b * NCHUNK + j) * HD + c;
    Ci[idx] = carry;
    carry = Ee[idx] + Pf[idx] * carry;
  }
}

template <int REV>
__global__ __launch_bounds__(256) void scan_p3(
    const unsigned short* __restrict__ gates, const float* __restrict__ Ci,
    unsigned short* __restrict__ hout) {
  const int c0 = threadIdx.x * 4;
  const int chunk = blockIdx.y, b = blockIdx.z;
  float h[4];
#pragma unroll
  for (int k = 0; k < 4; ++k)
    h[k] = Ci[((size_t)b * NCHUNK + chunk) * HD + c0 + k];
  for (int i = 0; i < CHUNKL; ++i) {
    const int p = chunk * CHUNKL + i;
    const int s = REV ? (S_LEN - 1 - p) : p;
    const size_t row = (size_t)b * S_LEN + s;
    const ushort4 Uv = *(const ushort4*)&gates[row * 2048 + c0];
    const ushort4 Av = *(const ushort4*)&gates[row * 2048 + 1024 + c0];
    const unsigned short* Up = (const unsigned short*)&Uv;
    const unsigned short* Ap = (const unsigned short*)&Av;
    ushort4 ho;
    unsigned short* hop = (unsigned short*)&ho;
#pragma unroll
    for (int k = 0; k < 4; ++k) {
      const float am1 = bf2f(Ap[k]);
      const float a = 1.0f - am1;
      const float xin =
          sqrtf(fmaxf(0.f, am1 * (2.0f - am1))) * bf2f(Up[k]);
      h[k] = fmaf(a, h[k], xin);
      hop[k] = f2bf(h[k]);
    }
    *(ushort4*)&hout[row * 2048 + c0] = ho;
  }
}

// ---------------- launcher ----------------
extern "C" void kernel_launch(void* const* d_in, const int* in_sizes, int n_in,
                              void* d_out, int out_size, void* d_ws,
                              size_t ws_size, hipStream_t stream) {
  const float* x = (const float*)d_in[0];
  const float* f_alog = (const float*)d_in[1];
  const float* f_Wx = (const float*)d_in[2];
  const float* f_bx = (const float*)d_in[3];
  const float* f_Wgx = (const float*)d_in[4];
  const float* f_bgx = (const float*)d_in[5];
  const float* f_Wga = (const float*)d_in[6];
  const float* f_bga = (const float*)d_in[7];
  const float* f_Wo = (const float*)d_in[8];
  const float* f_bo = (const float*)d_in[9];
  const float* b_alog = (const float*)d_in[10];
  const float* b_Wx = (const float*)d_in[11];
  const float* b_bx = (const float*)d_in[12];
  const float* b_Wgx = (const float*)d_in[13];
  const float* b_bgx = (const float*)d_in[14];
  const float* b_Wga = (const float*)d_in[15];
  const float* b_bga = (const float*)d_in[16];
  const float* b_Wo = (const float*)d_in[17];
  const float* b_bo = (const float*)d_in[18];
  const float* ld_W = (const float*)d_in[19];
  const float* ld_b = (const float*)d_in[20];
  float* out = (float*)d_out;
  (void)in_sizes; (void)n_in; (void)out_size;

  const size_t MB = 1ull << 20;
  if (ws_size < 159 * MB) return;  // fail clean, not fault
  const bool bigws = ws_size >= 191 * MB;  // room for bf16 residual copy

  char* ws = (char*)d_ws;
  unsigned short* B1T = (unsigned short*)(ws + 0 * MB);    // [2048][1024]
  unsigned short* B2Tf = (unsigned short*)(ws + 4 * MB);   // [2048][1024]
  unsigned short* B2Tb = (unsigned short*)(ws + 8 * MB);   // [2048][1024]
  unsigned short* B3T = (unsigned short*)(ws + 12 * MB);   // [1024][2048]
  unsigned short* B4T = (unsigned short*)(ws + 16 * MB);   // [1024][1024]
  float* b1 = (float*)(ws + 18 * MB);
  float* bgf = (float*)(ws + 18 * MB + 8192);
  float* bgb = (float*)(ws + 18 * MB + 16384);
  float* bos = (float*)(ws + 18 * MB + 24576);
  float* aef = (float*)(ws + 18 * MB + 32768);
  float* aeb = (float*)(ws + 18 * MB + 36864);
  unsigned short* x1b = (unsigned short*)(ws + 19 * MB);   // [16384][2048] bf16
  // region C (64 MB), time-shared: xg -> gates -> g2
  unsigned short* xg = (unsigned short*)(ws + 83 * MB);    // [16384][1024] bf16
  unsigned short* gates = (unsigned short*)(ws + 83 * MB); // [16384][2048] bf16
  unsigned short* g2 = (unsigned short*)(ws + 83 * MB);    // [16384][1024] bf16
  float* Pf = (float*)(ws + 147 * MB);                     // 2 MB
  float* Ee = (float*)(ws + 151 * MB);                     // 2 MB
  float* Ci = (float*)(ws + 155 * MB);                     // 2 MB
  unsigned short* xr = bigws ? (unsigned short*)(ws + 159 * MB) : nullptr;
  unsigned short* hcat = (unsigned short*)d_out;           // [16384][2048] bf16

  TArgs ta;
  ta.d[0] = {f_Wx, B1T, 1024, 0, 0};
  ta.d[1] = {b_Wx, B1T, 1024, 1024, 0};
  ta.d[2] = {f_Wgx, B2Tf, 1024, 0, 0};
  ta.d[3] = {f_Wga, B2Tf, 1024, 1024, 0};
  ta.d[4] = {b_Wgx, B2Tb, 1024, 0, 0};
  ta.d[5] = {b_Wga, B2Tb, 1024, 1024, 0};
  ta.d[6] = {f_Wo, B3T, 2048, 0, 0};
  ta.d[7] = {b_Wo, B3T, 2048, 0, 1024};
  ta.d[8] = {ld_W, B4T, 1024, 0, 0};

  transpose_pack<<<dim3(9 * 256), dim3(256), 0, stream>>>(ta);
  bias_pack<<<dim3(8), dim3(256), 0, stream>>>(
      f_bx, b_bx, f_bgx, f_bga, b_bgx, b_bga, f_bo, b_bo, f_alog, b_alog, b1,
      bgf, bgb, bos, aef, aeb);
  gelu_in<<<dim3(MROWS * HD / 4 / 256), dim3(256), 0, stream>>>(
      (const float4*)x, (ushort4*)xg, (ushort4*)xr);

  // G1: x1 = gelu(x) @ [Wx_f | Wx_b] + [bx_f | bx_b]   -> bf16 [16384][2048]
  gemm_bt<EPI_BF16><<<dim3(1024), dim3(512), 0, stream>>>(
      xg, 1024, B1T, 1024, 16, b1, nullptr, nullptr, nullptr, x1b, 2048);

  // fwd: fused gate ops (U, 1-a), then 3-phase scan -> hcat[:, 0:1024]
  gemm_bt<EPI_GATE><<<dim3(1024), dim3(512), 0, stream>>>(
      x1b, 2048, B2Tf, 1024, 16, bgf, x1b, aef, nullptr, gates, 2048);
  scan_p1<0><<<dim3(1, NCHUNK, NBATCH), dim3(256), 0, stream>>>(gates, Pf, Ee);
  scan_p2<<<dim3(16, NBATCH), dim3(64), 0, stream>>>(Pf, Ee, Ci);
  scan_p3<0><<<dim3(1, NCHUNK, NBATCH), dim3(256), 0, stream>>>(gates, Ci,
                                                                hcat);

  // bwd: fused gate ops (reusing gates), reverse scan -> hcat[:, 1024:2048]
  gemm_bt<EPI_GATE><<<dim3(1024), dim3(512), 0, stream>>>(
      x1b + 1024, 2048, B2Tb, 1024, 16, bgb, x1b + 1024, aeb, nullptr, gates,
      2048);
  scan_p1<1><<<dim3(1, NCHUNK, NBATCH), dim3(256), 0, stream>>>(gates, Pf, Ee);
  scan_p2<<<dim3(16, NBATCH), dim3(64), 0, stream>>>(Pf, Ee, Ci);
  scan_p3<1><<<dim3(1, NCHUNK, NBATCH), dim3(256), 0, stream>>>(gates, Ci,
                                                                hcat + 1024);

  // G3: g2 = gelu( ([h_f|h_b] @ [Wo_f;Wo_b] + bo_f+bo_b)/2 + x )
  // G4: out = g2 @ ld_W + ld_b + x
  if (bigws) {
    gemm_bt<EPI_X2, true><<<dim3(512), dim3(512), 0, stream>>>(
        hcat, 2048, B3T, 2048, 8, bos, xr, nullptr, nullptr, g2, 1024);
    gemm_bt<EPI_FINAL, true><<<dim3(512), dim3(512), 0, stream>>>(
        g2, 1024, B4T, 1024, 8, ld_b, xr, nullptr, out, nullptr, 1024);
  } else {
    gemm_bt<EPI_X2, false><<<dim3(512), dim3(512), 0, stream>>>(
        hcat, 2048, B3T, 2048, 8, bos, x, nullptr, nullptr, g2, 1024);
    gemm_bt<EPI_FINAL, false><<<dim3(512), dim3(512), 0, stream>>>(
        g2, 1024, B4T, 1024, 8, ld_b, x, nullptr, out, nullptr, 1024);
  }
}

// Round 23
// 526.130 us; speedup vs baseline: 1.0435x; 1.0435x over previous
//
#include <hip/hip_runtime.h>

typedef __attribute__((ext_vector_type(4))) float f32x4;
typedef __attribute__((ext_vector_type(8))) __bf16 bf16x8;
typedef __attribute__((ext_vector_type(8))) unsigned short u16x8;

#define DI __device__ __forceinline__

constexpr int S_LEN = 4096;
constexpr int NBATCH = 4;
constexpr int HD = 1024;
constexpr int MROWS = NBATCH * S_LEN;  // 16384
constexpr int NCHUNK = 128;
constexpr int CHUNKL = 32;

DI float bf2f(unsigned short u) {
  unsigned int x = ((unsigned int)u) << 16;
  return __builtin_bit_cast(float, x);
}
DI unsigned short f2bf(float f) {
  unsigned int u = __builtin_bit_cast(unsigned int, f);
  u += 0x7FFFu + ((u >> 16) & 1u);  // RNE; inputs finite
  return (unsigned short)(u >> 16);
}
DI float sigmoid_f(float x) { return 1.0f / (1.0f + expf(-x)); }
DI float gelu_f(float x) {
  float u = 0.7978845608028654f * (x + 0.044715f * x * x * x);
  return 0.5f * x * (1.0f + tanhf(u));
}
DI void gload16(const void* g, void* l) {
  __builtin_amdgcn_global_load_lds(
      (const __attribute__((address_space(1))) unsigned int*)g,
      (__attribute__((address_space(3))) unsigned int*)l, 16, 0, 0);
}

// ---------------- weight transpose+convert: dst[n][k] = bf16(src[k][n]) ----
struct TDesc {
  const float* src;       // [1024][1024] row-major
  unsigned short* dst;    // bf16 bits
  int ldDst;
  int rowOff;
  int colOff;
};
struct TArgs { TDesc d[9]; };

__global__ __launch_bounds__(256) void transpose_pack(TArgs args) {
  const int w = blockIdx.x >> 8;
  const int tile = blockIdx.x & 255;
  TDesc dd = args.d[w];
  const int tn = (tile & 15) * 64;
  const int tk = (tile >> 4) * 64;
  __shared__ float t[64][65];
  const int tx = threadIdx.x & 63, ty = threadIdx.x >> 6;
#pragma unroll
  for (int r = 0; r < 16; ++r) {
    int kk = ty * 16 + r;
    t[kk][tx] = dd.src[(size_t)(tk + kk) * 1024 + tn + tx];
  }
  __syncthreads();
#pragma unroll
  for (int r = 0; r < 16; ++r) {
    int nn = ty * 16 + r;
    dd.dst[(size_t)(dd.rowOff + tn + nn) * dd.ldDst + dd.colOff + tk + tx] =
        f2bf(t[tx][nn]);
  }
}

// ---------------- bias packing (+ sigmoid(a_logit) tables) ----------------
__global__ __launch_bounds__(256) void bias_pack(
    const float* bxf, const float* bxb, const float* bgxf, const float* bgaf,
    const float* bgxb, const float* bgab, const float* bof, const float* bob,
    const float* falog, const float* balog, float* b1, float* bgf, float* bgb,
    float* bos, float* aef, float* aeb) {
  int i = blockIdx.x * 256 + threadIdx.x;
  if (i < 1024) {
    b1[i] = bxf[i];
    bgf[i] = bgxf[i];
    bgb[i] = bgxb[i];
    bos[i] = bof[i] + bob[i];
    aef[i] = sigmoid_f(falog[i]);
    aeb[i] = sigmoid_f(balog[i]);
  } else if (i < 2048) {
    int j = i - 1024;
    b1[i] = bxb[j];
    bgf[i] = bgaf[j];
    bgb[i] = bgab[j];
  }
}

// ---------------- gelu(x) -> bf16 (+ bf16 copy of x) ----------------------
__global__ __launch_bounds__(256) void gelu_in(const float4* __restrict__ x,
                                               ushort4* __restrict__ xg,
                                               ushort4* __restrict__ xr) {
  int i = blockIdx.x * 256 + threadIdx.x;
  float4 v = x[i];
  ushort4 o;
  o.x = f2bf(gelu_f(v.x));
  o.y = f2bf(gelu_f(v.y));
  o.z = f2bf(gelu_f(v.z));
  o.w = f2bf(gelu_f(v.w));
  xg[i] = o;
  if (xr) {
    ushort4 p;
    p.x = f2bf(v.x);
    p.y = f2bf(v.y);
    p.z = f2bf(v.z);
    p.w = f2bf(v.w);
    xr[i] = p;
  }
}

// ---------------- GEMM: C = A[M x K] * BT[N x K]^T, fused epilogues --------
// R21 configuration (best measured, 530 us): BM=256 x BN=128, BK=64
// single-buffer (48 KB LDS), 512 threads (8 waves, 4M x 2N),
// __launch_bounds__(512,4), 1D XCD-chunked map. Vectorized epilogue:
// bv[j] <- B row wn+4r+j so each thread owns 4 consecutive output cols
// (ushort4/float4 stores + aux + bias). B swizzle f(R)=(R>>2)&7 pair:
// read slot (ks4+g)^((R>>2)&7), staging sg=(t&7)^((t>>5)&7). A unchanged.
enum { EPI_BF16 = 0, EPI_X2 = 2, EPI_FINAL = 3, EPI_GATE = 4 };

template <int EPI, bool AUXBF = false>
__global__ __launch_bounds__(512, 4) void gemm_bt(
    const unsigned short* __restrict__ A, int lda,
    const unsigned short* __restrict__ BT, int K, int nbx,
    const float* __restrict__ bias, const void* __restrict__ aux,
    const float* __restrict__ bias2, float* __restrict__ fout,
    unsigned short* __restrict__ bout, int ldo) {
  constexpr int BK = 64;
  __shared__ __align__(16) unsigned short lA[256 * BK];  // 32 KB
  __shared__ __align__(16) unsigned short lB[128 * BK];  // 16 KB
  const int t = threadIdx.x;
  const int lane = t & 63, wave = t >> 6;
  const int nwg = gridDim.x;  // multiple of 8
  int wg = blockIdx.x;
  wg = (wg & 7) * (nwg >> 3) + (wg >> 3);  // XCD-chunked, bijective
  const int by = wg / nbx, bx = wg - by * nbx;
  const int m0 = by * 256, n0 = bx * 128;
  const int wm = (wave >> 1) * 64, wn = (wave & 1) * 64;  // 4M x 2N
  f32x4 acc[4][4] = {};
  const int Rs = t >> 3;  // 0..63
  const int sgA = (t & 7) ^ (Rs & 7);
  const int sgB = (t & 7) ^ ((t >> 5) & 7);  // (R>>2)&7 swizzle, j-invariant
  const unsigned short* Ag = A + (size_t)(m0 + Rs) * lda + sgA * 8;
  const unsigned short* Bg = BT + (size_t)(n0 + Rs) * K + sgB * 8;
  const int r = lane & 15, g = lane >> 4;
  const int nK = K / BK;

  for (int kt = 0; kt < nK; ++kt) {
    __syncthreads();  // WAR
    {
      const unsigned short* a0 = Ag + kt * BK;
      const unsigned short* b0 = Bg + kt * BK;
      unsigned short* lAp = lA + t * 8;
      unsigned short* lBp = lB + t * 8;
#pragma unroll
      for (int j = 0; j < 4; ++j)
        gload16(a0 + (size_t)(j * 64) * lda, lAp + j * 4096);
#pragma unroll
      for (int j = 0; j < 2; ++j)
        gload16(b0 + (size_t)(j * 64) * K, lBp + j * 4096);
    }
    __syncthreads();  // RAW (vmcnt0 drain)
#pragma unroll
    for (int ks = 0; ks < 2; ++ks) {
      bf16x8 af[4], bv[4];
#pragma unroll
      for (int i = 0; i < 4; ++i) {
        const int R = wm + i * 16 + r;
        af[i] = __builtin_bit_cast(
            bf16x8,
            *(const u16x8*)&lA[R * BK + ((ks * 4 + g) ^ (R & 7)) * 8]);
      }
#pragma unroll
      for (int j = 0; j < 4; ++j) {
        const int R = wn + 4 * r + j;  // col permutation: 4 consecutive/thread
        bv[j] = __builtin_bit_cast(
            bf16x8,
            *(const u16x8*)&lB[R * BK + ((ks * 4 + g) ^ ((R >> 2) & 7)) * 8]);
      }
#pragma unroll
      for (int i = 0; i < 4; ++i)
#pragma unroll
        for (int j = 0; j < 4; ++j)
          acc[i][j] = __builtin_amdgcn_mfma_f32_16x16x32_bf16(
              af[i], bv[j], acc[i][j], 0, 0, 0);
    }
  }

  // epilogue: thread owns cols cb..cb+3 (consecutive) x rows (i,q)
  const int g4 = g * 4;
  const int cb = n0 + wn + 4 * r;
  const float4 bc4 = *(const float4*)&bias[cb];
  const float bcv[4] = {bc4.x, bc4.y, bc4.z, bc4.w};
#pragma unroll
  for (int i = 0; i < 4; ++i) {
#pragma unroll
    for (int q = 0; q < 4; ++q) {
      const int row = m0 + wm + i * 16 + g4 + q;
      const size_t o = (size_t)row * ldo + cb;
      float v[4];
#pragma unroll
      for (int j = 0; j < 4; ++j) v[j] = acc[i][j][q] + bcv[j];
      if constexpr (EPI == EPI_BF16) {
        ushort4 st = {f2bf(v[0]), f2bf(v[1]), f2bf(v[2]), f2bf(v[3])};
        *(ushort4*)&bout[o] = st;
      } else if constexpr (EPI == EPI_GATE) {
        if (cb < 1024) {
          // U = sig(gx_pre) * x1 ; aux = x1 (bf16, same layout as C)
          const ushort4 xa = *(const ushort4*)&((const unsigned short*)aux)[o];
          ushort4 st = {f2bf(sigmoid_f(v[0]) * bf2f(xa.x)),
                        f2bf(sigmoid_f(v[1]) * bf2f(xa.y)),
                        f2bf(sigmoid_f(v[2]) * bf2f(xa.z)),
                        f2bf(sigmoid_f(v[3]) * bf2f(xa.w))};
          *(ushort4*)&bout[o] = st;
        } else {
          // Am1 = 1 - a ; a = sig(ga_pre) * sig(a_logit)
          const float4 a4 = *(const float4*)&bias2[cb - 1024];
          const float ae[4] = {a4.x, a4.y, a4.z, a4.w};
          ushort4 st;
          unsigned short* sp = (unsigned short*)&st;
#pragma unroll
          for (int j = 0; j < 4; ++j)
            sp[j] = f2bf(1.0f - sigmoid_f(v[j]) * ae[j]);
          *(ushort4*)&bout[o] = st;
        }
      } else {
        float av[4];
        if constexpr (AUXBF) {
          const ushort4 xa = *(const ushort4*)&((const unsigned short*)aux)[o];
          av[0] = bf2f(xa.x); av[1] = bf2f(xa.y);
          av[2] = bf2f(xa.z); av[3] = bf2f(xa.w);
        } else {
          const float4 xa = *(const float4*)&((const float*)aux)[o];
          av[0] = xa.x; av[1] = xa.y; av[2] = xa.z; av[3] = xa.w;
        }
        if constexpr (EPI == EPI_X2) {
          ushort4 st;
          unsigned short* sp = (unsigned short*)&st;
#pragma unroll
          for (int j = 0; j < 4; ++j)
            sp[j] = f2bf(gelu_f(0.5f * v[j] + av[j]));
          *(ushort4*)&bout[o] = st;
        } else {  // EPI_FINAL
          float4 st = {v[0] + av[0], v[1] + av[1], v[2] + av[2], v[3] + av[3]};
          *(float4*)&fout[o] = st;
        }
      }
    }
  }
}

// ---------------- chunked linear scan h_t = a*h + xin ----------------------
// gates buffer: cols 0-1023 = U (sig(gx)*x1), cols 1024-2047 = Am1 = 1-a.
// a = 1-Am1; xin = sqrt(Am1*(2-Am1)) * U  (== sqrt(1-a^2)*gx*x1).
template <int REV>
__global__ __launch_bounds__(256) void scan_p1(
    const unsigned short* __restrict__ gates, float* __restrict__ Pf,
    float* __restrict__ Ee) {
  const int c0 = threadIdx.x * 4;
  const int chunk = blockIdx.y, b = blockIdx.z;
  float h[4] = {0.f, 0.f, 0.f, 0.f}, P[4] = {1.f, 1.f, 1.f, 1.f};
  for (int i = 0; i < CHUNKL; ++i) {
    const int p = chunk * CHUNKL + i;
    const int s = REV ? (S_LEN - 1 - p) : p;
    const size_t row = (size_t)b * S_LEN + s;
    const ushort4 Uv = *(const ushort4*)&gates[row * 2048 + c0];
    const ushort4 Av = *(const ushort4*)&gates[row * 2048 + 1024 + c0];
    const unsigned short* Up = (const unsigned short*)&Uv;
    const unsigned short* Ap = (const unsigned short*)&Av;
#pragma unroll
    for (int k = 0; k < 4; ++k) {
      const float am1 = bf2f(Ap[k]);
      const float a = 1.0f - am1;
      const float xin =
          sqrtf(fmaxf(0.f, am1 * (2.0f - am1))) * bf2f(Up[k]);
      h[k] = fmaf(a, h[k], xin);
      P[k] *= a;
    }
  }
  const size_t idx = ((size_t)b * NCHUNK + chunk) * HD + c0;
#pragma unroll
  for (int k = 0; k < 4; ++k) {
    Pf[idx + k] = P[k];
    Ee[idx + k] = h[k];
  }
}

// 1 channel/thread, 64-thread blocks, grid (16, NBATCH) = 64 blocks.
__global__ __launch_bounds__(64) void scan_p2(const float* __restrict__ Pf,
                                              const float* __restrict__ Ee,
                                              float* __restrict__ Ci) {
  const int c = blockIdx.x * 64 + threadIdx.x;
  const int b = blockIdx.y;
  float carry = 0.f;
#pragma unroll 4
  for (int j = 0; j < NCHUNK; ++j) {
    const size_t idx = ((size_t)b * NCHUNK + j) * HD + c;
    Ci[idx] = carry;
    carry = Ee[idx] + Pf[idx] * carry;
  }
}

template <int REV>
__global__ __launch_bounds__(256) void scan_p3(
    const unsigned short* __restrict__ gates, const float* __restrict__ Ci,
    unsigned short* __restrict__ hout) {
  const int c0 = threadIdx.x * 4;
  const int chunk = blockIdx.y, b = blockIdx.z;
  float h[4];
#pragma unroll
  for (int k = 0; k < 4; ++k)
    h[k] = Ci[((size_t)b * NCHUNK + chunk) * HD + c0 + k];
  for (int i = 0; i < CHUNKL; ++i) {
    const int p = chunk * CHUNKL + i;
    const int s = REV ? (S_LEN - 1 - p) : p;
    const size_t row = (size_t)b * S_LEN + s;
    const ushort4 Uv = *(const ushort4*)&gates[row * 2048 + c0];
    const ushort4 Av = *(const ushort4*)&gates[row * 2048 + 1024 + c0];
    const unsigned short* Up = (const unsigned short*)&Uv;
    const unsigned short* Ap = (const unsigned short*)&Av;
    ushort4 ho;
    unsigned short* hop = (unsigned short*)&ho;
#pragma unroll
    for (int k = 0; k < 4; ++k) {
      const float am1 = bf2f(Ap[k]);
      const float a = 1.0f - am1;
      const float xin =
          sqrtf(fmaxf(0.f, am1 * (2.0f - am1))) * bf2f(Up[k]);
      h[k] = fmaf(a, h[k], xin);
      hop[k] = f2bf(h[k]);
    }
    *(ushort4*)&hout[row * 2048 + c0] = ho;
  }
}

// ---------------- launcher ----------------
extern "C" void kernel_launch(void* const* d_in, const int* in_sizes, int n_in,
                              void* d_out, int out_size, void* d_ws,
                              size_t ws_size, hipStream_t stream) {
  const float* x = (const float*)d_in[0];
  const float* f_alog = (const float*)d_in[1];
  const float* f_Wx = (const float*)d_in[2];
  const float* f_bx = (const float*)d_in[3];
  const float* f_Wgx = (const float*)d_in[4];
  const float* f_bgx = (const float*)d_in[5];
  const float* f_Wga = (const float*)d_in[6];
  const float* f_bga = (const float*)d_in[7];
  const float* f_Wo = (const float*)d_in[8];
  const float* f_bo = (const float*)d_in[9];
  const float* b_alog = (const float*)d_in[10];
  const float* b_Wx = (const float*)d_in[11];
  const float* b_bx = (const float*)d_in[12];
  const float* b_Wgx = (const float*)d_in[13];
  const float* b_bgx = (const float*)d_in[14];
  const float* b_Wga = (const float*)d_in[15];
  const float* b_bga = (const float*)d_in[16];
  const float* b_Wo = (const float*)d_in[17];
  const float* b_bo = (const float*)d_in[18];
  const float* ld_W = (const float*)d_in[19];
  const float* ld_b = (const float*)d_in[20];
  float* out = (float*)d_out;
  (void)in_sizes; (void)n_in; (void)out_size;

  const size_t MB = 1ull << 20;
  if (ws_size < 159 * MB) return;  // fail clean, not fault
  const bool bigws = ws_size >= 191 * MB;  // room for bf16 residual copy

  char* ws = (char*)d_ws;
  unsigned short* B1T = (unsigned short*)(ws + 0 * MB);    // [2048][1024]
  unsigned short* B2Tf = (unsigned short*)(ws + 4 * MB);   // [2048][1024]
  unsigned short* B2Tb = (unsigned short*)(ws + 8 * MB);   // [2048][1024]
  unsigned short* B3T = (unsigned short*)(ws + 12 * MB);   // [1024][2048]
  unsigned short* B4T = (unsigned short*)(ws + 16 * MB);   // [1024][1024]
  float* b1 = (float*)(ws + 18 * MB);
  float* bgf = (float*)(ws + 18 * MB + 8192);
  float* bgb = (float*)(ws + 18 * MB + 16384);
  float* bos = (float*)(ws + 18 * MB + 24576);
  float* aef = (float*)(ws + 18 * MB + 32768);
  float* aeb = (float*)(ws + 18 * MB + 36864);
  unsigned short* x1b = (unsigned short*)(ws + 19 * MB);   // [16384][2048] bf16
  // region C (64 MB), time-shared: xg -> gates -> g2
  unsigned short* xg = (unsigned short*)(ws + 83 * MB);    // [16384][1024] bf16
  unsigned short* gates = (unsigned short*)(ws + 83 * MB); // [16384][2048] bf16
  unsigned short* g2 = (unsigned short*)(ws + 83 * MB);    // [16384][1024] bf16
  float* Pf = (float*)(ws + 147 * MB);                     // 2 MB
  float* Ee = (float*)(ws + 151 * MB);                     // 2 MB
  float* Ci = (float*)(ws + 155 * MB);                     // 2 MB
  unsigned short* xr = bigws ? (unsigned short*)(ws + 159 * MB) : nullptr;
  unsigned short* hcat = (unsigned short*)d_out;           // [16384][2048] bf16

  TArgs ta;
  ta.d[0] = {f_Wx, B1T, 1024, 0, 0};
  ta.d[1] = {b_Wx, B1T, 1024, 1024, 0};
  ta.d[2] = {f_Wgx, B2Tf, 1024, 0, 0};
  ta.d[3] = {f_Wga, B2Tf, 1024, 1024, 0};
  ta.d[4] = {b_Wgx, B2Tb, 1024, 0, 0};
  ta.d[5] = {b_Wga, B2Tb, 1024, 1024, 0};
  ta.d[6] = {f_Wo, B3T, 2048, 0, 0};
  ta.d[7] = {b_Wo, B3T, 2048, 0, 1024};
  ta.d[8] = {ld_W, B4T, 1024, 0, 0};

  transpose_pack<<<dim3(9 * 256), dim3(256), 0, stream>>>(ta);
  bias_pack<<<dim3(8), dim3(256), 0, stream>>>(
      f_bx, b_bx, f_bgx, f_bga, b_bgx, b_bga, f_bo, b_bo, f_alog, b_alog, b1,
      bgf, bgb, bos, aef, aeb);
  gelu_in<<<dim3(MROWS * HD / 4 / 256), dim3(256), 0, stream>>>(
      (const float4*)x, (ushort4*)xg, (ushort4*)xr);

  // G1: x1 = gelu(x) @ [Wx_f | Wx_b] + [bx_f | bx_b]   -> bf16 [16384][2048]
  gemm_bt<EPI_BF16><<<dim3(1024), dim3(512), 0, stream>>>(
      xg, 1024, B1T, 1024, 16, b1, nullptr, nullptr, nullptr, x1b, 2048);

  // fwd: fused gate ops (U, 1-a), then 3-phase scan -> hcat[:, 0:1024]
  gemm_bt<EPI_GATE><<<dim3(1024), dim3(512), 0, stream>>>(
      x1b, 2048, B2Tf, 1024, 16, bgf, x1b, aef, nullptr, gates, 2048);
  scan_p1<0><<<dim3(1, NCHUNK, NBATCH), dim3(256), 0, stream>>>(gates, Pf, Ee);
  scan_p2<<<dim3(16, NBATCH), dim3(64), 0, stream>>>(Pf, Ee, Ci);
  scan_p3<0><<<dim3(1, NCHUNK, NBATCH), dim3(256), 0, stream>>>(gates, Ci,
                                                                hcat);

  // bwd: fused gate ops (reusing gates), reverse scan -> hcat[:, 1024:2048]
  gemm_bt<EPI_GATE><<<dim3(1024), dim3(512), 0, stream>>>(
      x1b + 1024, 2048, B2Tb, 1024, 16, bgb, x1b + 1024, aeb, nullptr, gates,
      2048);
  scan_p1<1><<<dim3(1, NCHUNK, NBATCH), dim3(256), 0, stream>>>(gates, Pf, Ee);
  scan_p2<<<dim3(16, NBATCH), dim3(64), 0, stream>>>(Pf, Ee, Ci);
  scan_p3<1><<<dim3(1, NCHUNK, NBATCH), dim3(256), 0, stream>>>(gates, Ci,
                                                                hcat + 1024);

  // G3: g2 = gelu( ([h_f|h_b] @ [Wo_f;Wo_b] + bo_f+bo_b)/2 + x )
  // G4: out = g2 @ ld_W + ld_b + x
  if (bigws) {
    gemm_bt<EPI_X2, true><<<dim3(512), dim3(512), 0, stream>>>(
        hcat, 2048, B3T, 2048, 8, bos, xr, nullptr, nullptr, g2, 1024);
    gemm_bt<EPI_FINAL, true><<<dim3(512), dim3(512), 0, stream>>>(
        g2, 1024, B4T, 1024, 8, ld_b, xr, nullptr, out, nullptr, 1024);
  } else {
    gemm_bt<EPI_X2, false><<<dim3(512), dim3(512), 0, stream>>>(
        hcat, 2048, B3T, 2048, 8, bos, x, nullptr, nullptr, g2, 1024);
    gemm_bt<EPI_FINAL, false><<<dim3(512), dim3(512), 0, stream>>>(
        g2, 1024, B4T, 1024, 8, ld_b, x, nullptr, out, nullptr, 1024);
  }
}